// Round 2
// baseline (61.098 us; speedup 1.0000x reference)
//
#include <hip/hip_runtime.h>

// Problem constants: B=8, N=1024, F=128, H=4, K=32, TAU=1
#define BATCH 8   // points per barrier group
#define NBATCH 2  // batches per block
#define PPB (BATCH * NBATCH)

// ---------------------------------------------------------------------------
// Phase 1: S[bn][k] for all 8192 points.
// 512 blocks x 256 threads; thread t = (hk = t&127, half = t>>7) holds 64 key
// features in registers. Each block handles 16 points as 2 batches of 8.
// Per batch: distance accs for 8 points in regs -> LDS -> all-thread reduce
// (Student-t + per-head normalize) -> LDS -> conv-combine + softmax
// (8 points x 32 k = 256 threads). Only 2 barriers per 8 points.
// ---------------------------------------------------------------------------
__global__ __launch_bounds__(256, 4) void mempool_phase1(
    const float* __restrict__ x, const float* __restrict__ keys,
    const float* __restrict__ conv_w, float* __restrict__ S_out) {
  const int t = threadIdx.x;
  const int hk = t & 127;
  const int half = t >> 7;
  const float cw = conv_w[(t >> 5) & 3];

  // 64 key features (16 float4 = 64 VGPRs), register-resident.
  const float4* kq = reinterpret_cast<const float4*>(keys) + hk * 32 + half * 16;
  float4 key[16];
#pragma unroll
  for (int j = 0; j < 16; ++j) key[j] = kq[j];

  __shared__ float accs_lds[BATCH][2][128];  // 8 KB
  __shared__ float cwsn[BATCH][4][32];       // 4 KB

  const int base = blockIdx.x * PPB;
  for (int nb = 0; nb < NBATCH; ++nb) {
    const int b0 = base + nb * BATCH;
    const float4* xq =
        reinterpret_cast<const float4*>(x) + (size_t)b0 * 32 + half * 16;

    float acc[BATCH];
#pragma unroll
    for (int p = 0; p < BATCH; ++p) acc[p] = 0.f;

    // Distance compute: key chunk reused across 8 points; x loads are
    // wave-uniform (address independent of hk) -> broadcast, L1-served.
#pragma unroll
    for (int j = 0; j < 16; ++j) {
      const float4 kv = key[j];
#pragma unroll
      for (int p = 0; p < BATCH; ++p) {
        const float4 xv = xq[p * 32 + j];
        acc[p] += fabsf(kv.x - xv.x) + fabsf(kv.y - xv.y) +
                  fabsf(kv.z - xv.z) + fabsf(kv.w - xv.w);
      }
    }

#pragma unroll
    for (int p = 0; p < BATCH; ++p) accs_lds[p][half][hk] = acc[p];
    __syncthreads();

    // Reduce: thread t handles 4 (p, hk) pairs; 32-lane groups share (p, h).
#pragma unroll
    for (int i = 0; i < 4; ++i) {
      const int p = (t >> 7) + 2 * i;
      const float d = accs_lds[p][0][hk] + accs_lds[p][1][hk];
      const float tv = __builtin_amdgcn_rcpf(1.f + d * d);  // Student-t, tau=1
      float hs = tv;
#pragma unroll
      for (int m = 1; m < 32; m <<= 1) hs += __shfl_xor(hs, m);
      const float sn = tv * __builtin_amdgcn_rcpf(hs);  // per-head normalized
      cwsn[p][(hk >> 5)][hk & 31] = cw * sn;
    }
    __syncthreads();

    // Conv-combine over heads + softmax over k: thread = (p = t>>5, k = t&31).
    {
      const int p = t >> 5;
      const int k = t & 31;
      float sc = cwsn[p][0][k] + cwsn[p][1][k] + cwsn[p][2][k] + cwsn[p][3][k];
      float mx = sc;
#pragma unroll
      for (int m = 1; m < 32; m <<= 1) mx = fmaxf(mx, __shfl_xor(mx, m));
      const float e = __expf(sc - mx);
      float se = e;
#pragma unroll
      for (int m = 1; m < 32; m <<= 1) se += __shfl_xor(se, m);
      S_out[(size_t)(b0 + p) * 32 + k] = e * __builtin_amdgcn_rcpf(se);
    }
    // Next batch's first barrier (after accs_lds writes) protects cwsn reuse.
  }
}

// ---------------------------------------------------------------------------
// Phase 2 (unchanged): per (b,k):
//   pooled[f] = sum_n S[b][n][k] * x[b][n][f]
//   out[b][k][fo] = leakyrelu( pooled . lin_w[fo] )
// ---------------------------------------------------------------------------
__global__ __launch_bounds__(256) void mempool_phase2(
    const float* __restrict__ x, const float* __restrict__ S,
    const float* __restrict__ lin_w, float* __restrict__ out) {
  const int b = blockIdx.x >> 5;
  const int k = blockIdx.x & 31;
  const int t = threadIdx.x;
  const int fq = t & 31;
  const int seg = t >> 5;

  const float4* xq = reinterpret_cast<const float4*>(x) + (size_t)b * 1024 * 32;
  const float* Sb = S + (size_t)b * 1024 * 32 + k;

  float4 acc = {0.f, 0.f, 0.f, 0.f};
  const int n0 = seg * 128;
#pragma unroll 4
  for (int n = n0; n < n0 + 128; ++n) {
    const float sv = Sb[(size_t)n * 32];
    const float4 xv = xq[n * 32 + fq];
    acc.x += sv * xv.x;
    acc.y += sv * xv.y;
    acc.z += sv * xv.z;
    acc.w += sv * xv.w;
  }

  __shared__ float4 red[8][32];
  red[seg][fq] = acc;
  __syncthreads();

  __shared__ float4 pooled4[32];
  if (t < 32) {
    float4 a = red[0][t];
#pragma unroll
    for (int ss = 1; ss < 8; ++ss) {
      const float4 r = red[ss][t];
      a.x += r.x;
      a.y += r.y;
      a.z += r.z;
      a.w += r.w;
    }
    pooled4[t] = a;
  }
  __syncthreads();

  if (t < 128) {
    const float4* wq = reinterpret_cast<const float4*>(lin_w) + t * 32;
    float o = 0.f;
#pragma unroll
    for (int j = 0; j < 32; ++j) {
      const float4 w = wq[j];
      const float4 p = pooled4[j];
      o += w.x * p.x + w.y * p.y + w.z * p.z + w.w * p.w;
    }
    o = (o >= 0.f) ? o : 0.01f * o;
    out[(size_t)(b * 32 + k) * 128 + t] = o;
  }
}

extern "C" void kernel_launch(void* const* d_in, const int* in_sizes, int n_in,
                              void* d_out, int out_size, void* d_ws, size_t ws_size,
                              hipStream_t stream) {
  const float* x = (const float*)d_in[0];       // [8,1024,128]
  const float* keys = (const float*)d_in[1];    // [4,32,128]
  const float* conv_w = (const float*)d_in[2];  // [4]
  const float* lin_w = (const float*)d_in[3];   // [128,128]

  float* out = (float*)d_out;            // [8,32,128]
  float* S_out = (float*)d_out + 32768;  // [8,1024,32]

  mempool_phase1<<<8192 / PPB, 256, 0, stream>>>(x, keys, conv_w, S_out);
  mempool_phase2<<<8 * 32, 256, 0, stream>>>(x, S_out, lin_w, out);
}